// Round 1
// baseline (1754.764 us; speedup 1.0000x reference)
//
#include <hip/hip_runtime.h>

// Problem constants (from reference)
#define C_REL 5
#define NN    50000
#define EE    800000
#define D_IN  128
#define D_H   128
#define D_OUT 64

static constexpr int CN = C_REL * NN;            // 250000
static constexpr int CE = C_REL * EE;            // 4000000
static constexpr int SCAN_B = (NN + 255) / 256;  // 196 blocks per relation

// ---------------------------------------------------------------------------
// Prep kernels: degree, rsqrt, CSR build (all relations batched)
// ---------------------------------------------------------------------------

__global__ __launch_bounds__(256) void init_kernel(float* deg, int* cnt) {
  int i = blockIdx.x * 256 + threadIdx.x;
  if (i < CN) { deg[i] = 1.0f; cnt[i] = 0; }   // deg starts at 1 (self-loop w=1)
}

__global__ __launch_bounds__(256) void hist_kernel(const int* __restrict__ ei,
                                                   const float* __restrict__ ew,
                                                   float* deg, int* cnt) {
  int idx = blockIdx.x * 256 + threadIdx.x;
  if (idx >= CE) return;
  int c = idx / EE, e = idx - c * EE;
  int d = ei[(c * 2 + 1) * EE + e];
  float w = ew[idx];                             // ew[c*EE + e]
  atomicAdd(&deg[c * NN + d], w);
  atomicAdd(&cnt[c * NN + d], 1);
}

__global__ __launch_bounds__(256) void dis_kernel(float* deg) {
  int i = blockIdx.x * 256 + threadIdx.x;
  if (i < CN) deg[i] = rsqrtf(deg[i]);          // deg >= 1 always
}

__global__ __launch_bounds__(256) void scan_a_kernel(const int* __restrict__ cnt,
                                                     int* rowptr, int* bsum) {
  int c = blockIdx.x / SCAN_B;
  int b = blockIdx.x - c * SCAN_B;
  int tid = threadIdx.x;
  int i = b * 256 + tid;
  int val = (i < NN) ? cnt[c * NN + i] : 0;
  __shared__ int sh[256];
  sh[tid] = val;
  __syncthreads();
  for (int off = 1; off < 256; off <<= 1) {
    int t = (tid >= off) ? sh[tid - off] : 0;
    __syncthreads();
    sh[tid] += t;
    __syncthreads();
  }
  if (i < NN) rowptr[c * (NN + 1) + i + 1] = sh[tid];
  if (tid == 255) bsum[c * 256 + b] = sh[255];
}

__global__ __launch_bounds__(256) void scan_b_kernel(int* bsum) {
  int c = blockIdx.x;
  int tid = threadIdx.x;
  int val = (tid < SCAN_B) ? bsum[c * 256 + tid] : 0;
  __shared__ int sh[256];
  sh[tid] = val;
  __syncthreads();
  for (int off = 1; off < 256; off <<= 1) {
    int t = (tid >= off) ? sh[tid - off] : 0;
    __syncthreads();
    sh[tid] += t;
    __syncthreads();
  }
  bsum[c * 256 + tid] = sh[tid] - val;          // exclusive
}

__global__ __launch_bounds__(256) void scan_c_kernel(int* rowptr, const int* __restrict__ bsum) {
  int c = blockIdx.x / SCAN_B;
  int b = blockIdx.x - c * SCAN_B;
  int i = b * 256 + threadIdx.x;
  if (i < NN) rowptr[c * (NN + 1) + i + 1] += bsum[c * 256 + b];
  if (i == 0) rowptr[c * (NN + 1)] = 0;
}

__global__ __launch_bounds__(256) void cursor_kernel(int* cursor, const int* __restrict__ rowptr) {
  int i = blockIdx.x * 256 + threadIdx.x;
  if (i >= CN) return;
  int c = i / NN, n = i - c * NN;
  cursor[i] = rowptr[c * (NN + 1) + n];
}

__global__ __launch_bounds__(256) void fill_kernel(const int* __restrict__ ei,
                                                   const float* __restrict__ ew,
                                                   const float* __restrict__ dis,
                                                   int* cursor, int* csr_src, float* csr_norm) {
  int idx = blockIdx.x * 256 + threadIdx.x;
  if (idx >= CE) return;
  int c = idx / EE, e = idx - c * EE;
  int s = ei[(c * 2 + 0) * EE + e];
  int d = ei[(c * 2 + 1) * EE + e];
  float w = ew[idx];
  float nrm = dis[c * NN + s] * w * dis[c * NN + d];
  int pos = atomicAdd(&cursor[c * NN + d], 1);
  csr_src[c * EE + pos] = s;
  csr_norm[c * EE + pos] = nrm;
}

// ---------------------------------------------------------------------------
// fp32 GEMM: h[M x NC] = A[M x 128] @ B[128 x NC], B fully LDS-resident.
// Block = 256 threads, 64-row tile, per-thread 8 rows x (NC/32) cols.
// ---------------------------------------------------------------------------

template <int NC>
__global__ __launch_bounds__(256) void gemm_kernel(const float* __restrict__ A,
                                                   const float* __restrict__ B,
                                                   float* __restrict__ Cout, int M) {
  constexpr int K = 128;
  constexpr int KC = 32;
  constexpr int CPT = NC / 32;                   // cols per thread: 4 or 2
  __shared__ float Bs[K * NC];
  __shared__ float As[64][KC + 4];

  int tid = threadIdx.x;
  // Load whole B into LDS (coalesced float4)
  {
    const float4* B4 = (const float4*)B;
    float4* Bs4 = (float4*)Bs;
    for (int i = tid; i < K * NC / 4; i += 256) Bs4[i] = B4[i];
  }
  int tx = tid & 31;
  int ty = tid >> 5;
  int rowBase = blockIdx.x * 64;

  float acc[8][CPT];
#pragma unroll
  for (int i = 0; i < 8; ++i)
#pragma unroll
    for (int j = 0; j < CPT; ++j) acc[i][j] = 0.f;

  for (int kc = 0; kc < K; kc += KC) {
    __syncthreads();
    // Stage A tile [64][32]
    int lr = tid >> 3;
    int lc = (tid & 7) * 4;
#pragma unroll
    for (int rr = 0; rr < 64; rr += 32) {
      int r = lr + rr;
      int gr = rowBase + r;
      float4 v = make_float4(0.f, 0.f, 0.f, 0.f);
      if (gr < M) v = *(const float4*)&A[(size_t)gr * K + kc + lc];
      *(float4*)&As[r][lc] = v;
    }
    __syncthreads();

#pragma unroll
    for (int kk = 0; kk < KC; kk += 4) {
      float4 av[8];
#pragma unroll
      for (int i = 0; i < 8; ++i) av[i] = *(const float4*)&As[ty * 8 + i][kk];
#pragma unroll
      for (int u = 0; u < 4; ++u) {
        int k = kc + kk + u;
        if constexpr (CPT == 4) {
          float4 bv = *(const float4*)&Bs[k * NC + tx * 4];
#pragma unroll
          for (int i = 0; i < 8; ++i) {
            float a = ((const float*)&av[i])[u];
            acc[i][0] += a * bv.x;
            acc[i][1] += a * bv.y;
            acc[i][2] += a * bv.z;
            acc[i][3] += a * bv.w;
          }
        } else {
          float2 bv = *(const float2*)&Bs[k * NC + tx * 2];
#pragma unroll
          for (int i = 0; i < 8; ++i) {
            float a = ((const float*)&av[i])[u];
            acc[i][0] += a * bv.x;
            acc[i][1] += a * bv.y;
          }
        }
      }
    }
  }

#pragma unroll
  for (int i = 0; i < 8; ++i) {
    int gr = rowBase + ty * 8 + i;
    if (gr >= M) continue;
    if constexpr (CPT == 4) {
      *(float4*)&Cout[(size_t)gr * NC + tx * 4] =
          make_float4(acc[i][0], acc[i][1], acc[i][2], acc[i][3]);
    } else {
      *(float2*)&Cout[(size_t)gr * NC + tx * 2] = make_float2(acc[i][0], acc[i][1]);
    }
  }
}

// ---------------------------------------------------------------------------
// CSR aggregation: one wave per node. acc = bias + dis^2*h[n] + sum norm*h[src]
// ---------------------------------------------------------------------------

template <int F, bool RELU>
__global__ __launch_bounds__(256) void agg_kernel(const float* __restrict__ h,
                                                  const int* __restrict__ rowptr,
                                                  const int* __restrict__ csr_src,
                                                  const float* __restrict__ csr_norm,
                                                  const float* __restrict__ dis,
                                                  const float* __restrict__ bias,
                                                  float* __restrict__ out) {
  int node = blockIdx.x * 4 + (threadIdx.x >> 6);
  int lane = threadIdx.x & 63;
  if (node >= NN) return;
  float dn = dis[node];
  float sn = dn * dn;   // self-loop norm = dis*1*dis
  int beg = rowptr[node];
  int end = rowptr[node + 1];

  if constexpr (F == 128) {
    int f = lane * 2;
    float a0 = bias[f], a1 = bias[f + 1];
    float2 hv = *(const float2*)&h[(size_t)node * F + f];
    a0 += sn * hv.x;
    a1 += sn * hv.y;
    for (int idx = beg; idx < end; ++idx) {
      int s = csr_src[idx];
      float nm = csr_norm[idx];
      float2 v = *(const float2*)&h[(size_t)s * F + f];
      a0 += nm * v.x;
      a1 += nm * v.y;
    }
    if (RELU) { a0 = fmaxf(a0, 0.f); a1 = fmaxf(a1, 0.f); }
    *(float2*)&out[(size_t)node * F + f] = make_float2(a0, a1);
  } else {
    int f = lane;
    float a0 = bias[f] + sn * h[(size_t)node * F + f];
    for (int idx = beg; idx < end; ++idx) {
      a0 += csr_norm[idx] * h[(size_t)csr_src[idx] * F + f];
    }
    if (RELU) a0 = fmaxf(a0, 0.f);
    out[(size_t)node * F + f] = a0;
  }
}

// ---------------------------------------------------------------------------
// Host launcher
// ---------------------------------------------------------------------------

extern "C" void kernel_launch(void* const* d_in, const int* in_sizes, int n_in,
                              void* d_out, int out_size, void* d_ws, size_t ws_size,
                              hipStream_t stream) {
  const float* x  = (const float*)d_in[0];   // [C][N][128]
  const int*   ei = (const int*)d_in[1];     // [C][2][E]
  const float* ew = (const float*)d_in[2];   // [C][E]
  const float* W1 = (const float*)d_in[3];   // [C][128][128]
  const float* b1 = (const float*)d_in[4];   // [C][128]
  const float* W2 = (const float*)d_in[5];   // [C][128][64]
  const float* b2 = (const float*)d_in[6];   // [C][64]
  float* out = (float*)d_out;                // [C][N][64]

  // Workspace layout (256B aligned)
  char* ws = (char*)d_ws;
  size_t off = 0;
  auto alloc = [&](size_t bytes) {
    size_t cur = off;
    off += (bytes + 255) & ~(size_t)255;
    return cur;
  };
  float* deg      = (float*)(ws + alloc((size_t)CN * 4));
  int*   cnt      = (int*)  (ws + alloc((size_t)CN * 4));
  int*   rowptr   = (int*)  (ws + alloc((size_t)C_REL * (NN + 1) * 4));
  int*   cursor   = (int*)  (ws + alloc((size_t)CN * 4));
  int*   bsum     = (int*)  (ws + alloc((size_t)C_REL * 256 * 4));
  int*   csr_src  = (int*)  (ws + alloc((size_t)CE * 4));
  float* csr_norm = (float*)(ws + alloc((size_t)CE * 4));
  float* h1       = (float*)(ws + alloc((size_t)NN * D_H * 4));   // also holds h2
  float* agg1     = (float*)(ws + alloc((size_t)NN * D_H * 4));

  const int NB_CN = (CN + 255) / 256;     // 977
  const int NB_CE = (CE + 255) / 256;     // 15625

  init_kernel<<<NB_CN, 256, 0, stream>>>(deg, cnt);
  hist_kernel<<<NB_CE, 256, 0, stream>>>(ei, ew, deg, cnt);
  dis_kernel<<<NB_CN, 256, 0, stream>>>(deg);
  scan_a_kernel<<<C_REL * SCAN_B, 256, 0, stream>>>(cnt, rowptr, bsum);
  scan_b_kernel<<<C_REL, 256, 0, stream>>>(bsum);
  scan_c_kernel<<<C_REL * SCAN_B, 256, 0, stream>>>(rowptr, bsum);
  cursor_kernel<<<NB_CN, 256, 0, stream>>>(cursor, rowptr);
  fill_kernel<<<NB_CE, 256, 0, stream>>>(ei, ew, deg, cursor, csr_src, csr_norm);

  const int NB_GEMM = (NN + 63) / 64;     // 782
  const int NB_AGG  = NN / 4;             // 12500

  for (int c = 0; c < C_REL; ++c) {
    const float* xc   = x  + (size_t)c * NN * D_IN;
    const float* W1c  = W1 + (size_t)c * D_IN * D_H;
    const float* b1c  = b1 + (size_t)c * D_H;
    const float* W2c  = W2 + (size_t)c * D_H * D_OUT;
    const float* b2c  = b2 + (size_t)c * D_OUT;
    const int*   rpc  = rowptr + (size_t)c * (NN + 1);
    const int*   csc  = csr_src + (size_t)c * EE;
    const float* cnc  = csr_norm + (size_t)c * EE;
    const float* disc = deg + (size_t)c * NN;
    float* outc = out + (size_t)c * NN * D_OUT;

    // Layer 1: h1 = x @ W1 ; agg1 = relu(bias + propagate(h1))
    gemm_kernel<D_H><<<NB_GEMM, 256, 0, stream>>>(xc, W1c, h1, NN);
    agg_kernel<D_H, true><<<NB_AGG, 256, 0, stream>>>(h1, rpc, csc, cnc, disc, b1c, agg1);
    // Layer 2: h2 = agg1 @ W2 (reuse h1 buffer) ; out = bias + propagate(h2)
    gemm_kernel<D_OUT><<<NB_GEMM, 256, 0, stream>>>(agg1, W2c, h1, NN);
    agg_kernel<D_OUT, false><<<NB_AGG, 256, 0, stream>>>(h1, rpc, csc, cnc, disc, b2c, outc);
  }
}

// Round 2
// 1490.404 us; speedup vs baseline: 1.1774x; 1.1774x over previous
//
#include <hip/hip_runtime.h>

// Problem constants (from reference)
#define C_REL 5
#define NN    50000
#define EE    800000
#define D_IN  128
#define D_H   128
#define D_OUT 64

static constexpr int CN = C_REL * NN;            // 250000
static constexpr int CE = C_REL * EE;            // 4000000
static constexpr int SCAN_B = (NN + 255) / 256;  // 196 blocks per relation

static constexpr unsigned long long MASK40 = (1ULL << 40) - 1;
static constexpr float FIX_SCALE = 16777216.0f;       // 2^24
static constexpr float FIX_INV   = 1.0f / 16777216.0f;

// ---------------------------------------------------------------------------
// Prep: packed (cnt<<40 | fixpoint weight-sum) histogram, one atomic per edge.
// The atomic's return value is the edge's rank within its dst bucket.
// ---------------------------------------------------------------------------

__global__ __launch_bounds__(256) void init_kernel(unsigned long long* packed) {
  int i = blockIdx.x * 256 + threadIdx.x;
  if (i < CN) packed[i] = 0ULL;
}

__global__ __launch_bounds__(256) void hist_kernel(const int* __restrict__ ei,
                                                   const float* __restrict__ ew,
                                                   unsigned long long* packed,
                                                   int* __restrict__ pos) {
  int idx = blockIdx.x * 256 + threadIdx.x;
  if (idx >= CE) return;
  int c = idx / EE, e = idx - c * EE;
  int d = ei[(c * 2 + 1) * EE + e];
  float w = ew[idx];
  unsigned long long wfix = (unsigned long long)(w * FIX_SCALE + 0.5f);
  unsigned long long old = atomicAdd(&packed[c * NN + d], (1ULL << 40) | wfix);
  pos[idx] = (int)(old >> 40);
}

__global__ __launch_bounds__(256) void dis_kernel(const unsigned long long* __restrict__ packed,
                                                  float* __restrict__ dis) {
  int i = blockIdx.x * 256 + threadIdx.x;
  if (i >= CN) return;
  float deg = 1.0f + (float)(packed[i] & MASK40) * FIX_INV;  // self-loop w=1
  dis[i] = rsqrtf(deg);
}

__global__ __launch_bounds__(256) void scan_a_kernel(const unsigned long long* __restrict__ packed,
                                                     int* rowptr, int* bsum) {
  int c = blockIdx.x / SCAN_B;
  int b = blockIdx.x - c * SCAN_B;
  int tid = threadIdx.x;
  int i = b * 256 + tid;
  int val = (i < NN) ? (int)(packed[c * NN + i] >> 40) : 0;
  __shared__ int sh[256];
  sh[tid] = val;
  __syncthreads();
  for (int off = 1; off < 256; off <<= 1) {
    int t = (tid >= off) ? sh[tid - off] : 0;
    __syncthreads();
    sh[tid] += t;
    __syncthreads();
  }
  if (i < NN) rowptr[c * (NN + 1) + i + 1] = sh[tid];
  if (tid == 255) bsum[c * 256 + b] = sh[255];
}

__global__ __launch_bounds__(256) void scan_b_kernel(int* bsum) {
  int c = blockIdx.x;
  int tid = threadIdx.x;
  int val = (tid < SCAN_B) ? bsum[c * 256 + tid] : 0;
  __shared__ int sh[256];
  sh[tid] = val;
  __syncthreads();
  for (int off = 1; off < 256; off <<= 1) {
    int t = (tid >= off) ? sh[tid - off] : 0;
    __syncthreads();
    sh[tid] += t;
    __syncthreads();
  }
  bsum[c * 256 + tid] = sh[tid] - val;          // exclusive
}

__global__ __launch_bounds__(256) void scan_c_kernel(int* rowptr, const int* __restrict__ bsum) {
  int c = blockIdx.x / SCAN_B;
  int b = blockIdx.x - c * SCAN_B;
  int i = b * 256 + threadIdx.x;
  if (i < NN) rowptr[c * (NN + 1) + i + 1] += bsum[c * 256 + b];
  if (i == 0) rowptr[c * (NN + 1)] = 0;
}

// fill: atomic-free. slot = rowptr[d] + pos[e]; one 8B scattered write.
__global__ __launch_bounds__(256) void fill_kernel(const int* __restrict__ ei,
                                                   const float* __restrict__ ew,
                                                   const float* __restrict__ dis,
                                                   const int* __restrict__ rowptr,
                                                   const int* __restrict__ pos,
                                                   int2* __restrict__ csr) {
  int idx = blockIdx.x * 256 + threadIdx.x;
  if (idx >= CE) return;
  int c = idx / EE, e = idx - c * EE;
  int s = ei[(c * 2 + 0) * EE + e];
  int d = ei[(c * 2 + 1) * EE + e];
  float w = ew[idx];
  float nrm = dis[c * NN + s] * w * dis[c * NN + d];
  int slot = rowptr[c * (NN + 1) + d] + pos[idx];
  csr[c * EE + slot] = make_int2(s, __float_as_int(nrm));
}

// ---------------------------------------------------------------------------
// fp32 GEMM: h[M x NC] = A[M x 128] @ B[128 x NC], B fully LDS-resident.
// Block = 256 threads, 64-row tile, per-thread 8 rows x (NC/32) cols.
// ---------------------------------------------------------------------------

template <int NC>
__global__ __launch_bounds__(256) void gemm_kernel(const float* __restrict__ A,
                                                   const float* __restrict__ B,
                                                   float* __restrict__ Cout, int M) {
  constexpr int K = 128;
  constexpr int KC = 32;
  constexpr int CPT = NC / 32;                   // cols per thread: 4 or 2
  __shared__ float Bs[K * NC];
  __shared__ float As[64][KC + 4];

  int tid = threadIdx.x;
  {
    const float4* B4 = (const float4*)B;
    float4* Bs4 = (float4*)Bs;
    for (int i = tid; i < K * NC / 4; i += 256) Bs4[i] = B4[i];
  }
  int tx = tid & 31;
  int ty = tid >> 5;
  int rowBase = blockIdx.x * 64;

  float acc[8][CPT];
#pragma unroll
  for (int i = 0; i < 8; ++i)
#pragma unroll
    for (int j = 0; j < CPT; ++j) acc[i][j] = 0.f;

  for (int kc = 0; kc < K; kc += KC) {
    __syncthreads();
    int lr = tid >> 3;
    int lc = (tid & 7) * 4;
#pragma unroll
    for (int rr = 0; rr < 64; rr += 32) {
      int r = lr + rr;
      int gr = rowBase + r;
      float4 v = make_float4(0.f, 0.f, 0.f, 0.f);
      if (gr < M) v = *(const float4*)&A[(size_t)gr * K + kc + lc];
      *(float4*)&As[r][lc] = v;
    }
    __syncthreads();

#pragma unroll
    for (int kk = 0; kk < KC; kk += 4) {
      float4 av[8];
#pragma unroll
      for (int i = 0; i < 8; ++i) av[i] = *(const float4*)&As[ty * 8 + i][kk];
#pragma unroll
      for (int u = 0; u < 4; ++u) {
        int k = kc + kk + u;
        if constexpr (CPT == 4) {
          float4 bv = *(const float4*)&Bs[k * NC + tx * 4];
#pragma unroll
          for (int i = 0; i < 8; ++i) {
            float a = ((const float*)&av[i])[u];
            acc[i][0] += a * bv.x;
            acc[i][1] += a * bv.y;
            acc[i][2] += a * bv.z;
            acc[i][3] += a * bv.w;
          }
        } else {
          float2 bv = *(const float2*)&Bs[k * NC + tx * 2];
#pragma unroll
          for (int i = 0; i < 8; ++i) {
            float a = ((const float*)&av[i])[u];
            acc[i][0] += a * bv.x;
            acc[i][1] += a * bv.y;
          }
        }
      }
    }
  }

#pragma unroll
  for (int i = 0; i < 8; ++i) {
    int gr = rowBase + ty * 8 + i;
    if (gr >= M) continue;
    if constexpr (CPT == 4) {
      *(float4*)&Cout[(size_t)gr * NC + tx * 4] =
          make_float4(acc[i][0], acc[i][1], acc[i][2], acc[i][3]);
    } else {
      *(float2*)&Cout[(size_t)gr * NC + tx * 2] = make_float2(acc[i][0], acc[i][1]);
    }
  }
}

// ---------------------------------------------------------------------------
// CSR aggregation: one wave per node. acc = bias + dis^2*h[n] + sum norm*h[src]
// CSR entry = int2(src, bitcast norm): one 8B broadcast load per edge.
// ---------------------------------------------------------------------------

template <int F, bool RELU>
__global__ __launch_bounds__(256) void agg_kernel(const float* __restrict__ h,
                                                  const int* __restrict__ rowptr,
                                                  const int2* __restrict__ csr,
                                                  const float* __restrict__ dis,
                                                  const float* __restrict__ bias,
                                                  float* __restrict__ out) {
  int node = blockIdx.x * 4 + (threadIdx.x >> 6);
  int lane = threadIdx.x & 63;
  if (node >= NN) return;
  float dn = dis[node];
  float sn = dn * dn;   // self-loop norm = dis*1*dis
  int beg = rowptr[node];
  int end = rowptr[node + 1];

  if constexpr (F == 128) {
    int f = lane * 2;
    float a0 = bias[f], a1 = bias[f + 1];
    float2 hv = *(const float2*)&h[(size_t)node * F + f];
    a0 += sn * hv.x;
    a1 += sn * hv.y;
    for (int idx = beg; idx < end; ++idx) {
      int2 en = csr[idx];
      float nm = __int_as_float(en.y);
      float2 v = *(const float2*)&h[(size_t)en.x * F + f];
      a0 += nm * v.x;
      a1 += nm * v.y;
    }
    if (RELU) { a0 = fmaxf(a0, 0.f); a1 = fmaxf(a1, 0.f); }
    *(float2*)&out[(size_t)node * F + f] = make_float2(a0, a1);
  } else {
    int f = lane;
    float a0 = bias[f] + sn * h[(size_t)node * F + f];
    for (int idx = beg; idx < end; ++idx) {
      int2 en = csr[idx];
      a0 += __int_as_float(en.y) * h[(size_t)en.x * F + f];
    }
    if (RELU) a0 = fmaxf(a0, 0.f);
    out[(size_t)node * F + f] = a0;
  }
}

// ---------------------------------------------------------------------------
// Host launcher
// ---------------------------------------------------------------------------

extern "C" void kernel_launch(void* const* d_in, const int* in_sizes, int n_in,
                              void* d_out, int out_size, void* d_ws, size_t ws_size,
                              hipStream_t stream) {
  const float* x  = (const float*)d_in[0];   // [C][N][128]
  const int*   ei = (const int*)d_in[1];     // [C][2][E]
  const float* ew = (const float*)d_in[2];   // [C][E]
  const float* W1 = (const float*)d_in[3];   // [C][128][128]
  const float* b1 = (const float*)d_in[4];   // [C][128]
  const float* W2 = (const float*)d_in[5];   // [C][128][64]
  const float* b2 = (const float*)d_in[6];   // [C][64]
  float* out = (float*)d_out;                // [C][N][64]

  // Workspace layout (256B aligned)
  char* ws = (char*)d_ws;
  size_t off = 0;
  auto alloc = [&](size_t bytes) {
    size_t cur = off;
    off += (bytes + 255) & ~(size_t)255;
    return cur;
  };
  unsigned long long* packed = (unsigned long long*)(ws + alloc((size_t)CN * 8));
  float* dis      = (float*)(ws + alloc((size_t)CN * 4));
  int*   rowptr   = (int*)  (ws + alloc((size_t)C_REL * (NN + 1) * 4));
  int*   bsum     = (int*)  (ws + alloc((size_t)C_REL * 256 * 4));
  int2*  csr      = (int2*) (ws + alloc((size_t)CE * 8));
  float* h1       = (float*)(ws + alloc((size_t)NN * D_H * 4));   // also holds h2
  float* agg1     = (float*)(ws + alloc((size_t)NN * D_H * 4));
  // pos[CE] (16MB) unions with h1 (25.6MB): dead before first GEMM writes h1.
  int* pos = (int*)h1;

  const int NB_CN = (CN + 255) / 256;     // 977
  const int NB_CE = (CE + 255) / 256;     // 15625

  init_kernel<<<NB_CN, 256, 0, stream>>>(packed);
  hist_kernel<<<NB_CE, 256, 0, stream>>>(ei, ew, packed, pos);
  dis_kernel<<<NB_CN, 256, 0, stream>>>(packed, dis);
  scan_a_kernel<<<C_REL * SCAN_B, 256, 0, stream>>>(packed, rowptr, bsum);
  scan_b_kernel<<<C_REL, 256, 0, stream>>>(bsum);
  scan_c_kernel<<<C_REL * SCAN_B, 256, 0, stream>>>(rowptr, bsum);
  fill_kernel<<<NB_CE, 256, 0, stream>>>(ei, ew, dis, rowptr, pos, csr);

  const int NB_GEMM = (NN + 63) / 64;     // 782
  const int NB_AGG  = NN / 4;             // 12500

  for (int c = 0; c < C_REL; ++c) {
    const float* xc   = x  + (size_t)c * NN * D_IN;
    const float* W1c  = W1 + (size_t)c * D_IN * D_H;
    const float* b1c  = b1 + (size_t)c * D_H;
    const float* W2c  = W2 + (size_t)c * D_H * D_OUT;
    const float* b2c  = b2 + (size_t)c * D_OUT;
    const int*   rpc  = rowptr + (size_t)c * (NN + 1);
    const int2*  csc  = csr + (size_t)c * EE;
    const float* disc = dis + (size_t)c * NN;
    float* outc = out + (size_t)c * NN * D_OUT;

    // Layer 1: h1 = x @ W1 ; agg1 = relu(bias + propagate(h1))
    gemm_kernel<D_H><<<NB_GEMM, 256, 0, stream>>>(xc, W1c, h1, NN);
    agg_kernel<D_H, true><<<NB_AGG, 256, 0, stream>>>(h1, rpc, csc, disc, b1c, agg1);
    // Layer 2: h2 = agg1 @ W2 (reuse h1 buffer) ; out = bias + propagate(h2)
    gemm_kernel<D_OUT><<<NB_GEMM, 256, 0, stream>>>(agg1, W2c, h1, NN);
    agg_kernel<D_OUT, false><<<NB_AGG, 256, 0, stream>>>(h1, rpc, csc, disc, b2c, outc);
  }
}

// Round 3
// 1378.938 us; speedup vs baseline: 1.2725x; 1.0808x over previous
//
#include <hip/hip_runtime.h>

// Problem constants (from reference)
#define C_REL 5
#define NN    50000
#define EE    800000
#define D_IN  128
#define D_H   128
#define D_OUT 64

static constexpr int CN = C_REL * NN;            // 250000
static constexpr int CE = C_REL * EE;            // 4000000
static constexpr int SCAN_B = (NN + 255) / 256;  // 196 blocks per relation
static constexpr int BLK_GEMM_REL = (NN + 63) / 64;   // 782
static constexpr int BLK_AGG_REL  = NN / 4;           // 12500

static constexpr unsigned long long MASK40 = (1ULL << 40) - 1;
static constexpr float FIX_SCALE = 16777216.0f;       // 2^24
static constexpr float FIX_INV   = 1.0f / 16777216.0f;

// ---------------------------------------------------------------------------
// Prep: packed (cnt<<40 | fixpoint weight-sum) histogram, one atomic per edge.
// Grid-stride (4096 blocks) to amortize block launch.
// ---------------------------------------------------------------------------

__global__ __launch_bounds__(256) void init_kernel(unsigned long long* packed) {
  int i = blockIdx.x * 256 + threadIdx.x;
  if (i < CN) packed[i] = 0ULL;
}

__global__ __launch_bounds__(256) void hist_kernel(const int* __restrict__ ei,
                                                   const float* __restrict__ ew,
                                                   unsigned long long* packed,
                                                   int* __restrict__ pos) {
  int stride = gridDim.x * 256;
  for (int idx = blockIdx.x * 256 + threadIdx.x; idx < CE; idx += stride) {
    int c = idx / EE, e = idx - c * EE;
    int d = ei[(c * 2 + 1) * EE + e];
    float w = ew[idx];
    unsigned long long wfix = (unsigned long long)(w * FIX_SCALE + 0.5f);
    unsigned long long old = atomicAdd(&packed[c * NN + d], (1ULL << 40) | wfix);
    pos[idx] = (int)(old >> 40);
  }
}

__global__ __launch_bounds__(256) void dis_kernel(const unsigned long long* __restrict__ packed,
                                                  float* __restrict__ dis) {
  int i = blockIdx.x * 256 + threadIdx.x;
  if (i >= CN) return;
  float deg = 1.0f + (float)(packed[i] & MASK40) * FIX_INV;  // self-loop w=1
  dis[i] = rsqrtf(deg);
}

__global__ __launch_bounds__(256) void scan_a_kernel(const unsigned long long* __restrict__ packed,
                                                     int* rowptr, int* bsum) {
  int c = blockIdx.x / SCAN_B;
  int b = blockIdx.x - c * SCAN_B;
  int tid = threadIdx.x;
  int i = b * 256 + tid;
  int val = (i < NN) ? (int)(packed[c * NN + i] >> 40) : 0;
  __shared__ int sh[256];
  sh[tid] = val;
  __syncthreads();
  for (int off = 1; off < 256; off <<= 1) {
    int t = (tid >= off) ? sh[tid - off] : 0;
    __syncthreads();
    sh[tid] += t;
    __syncthreads();
  }
  if (i < NN) rowptr[c * (NN + 1) + i + 1] = sh[tid];
  if (tid == 255) bsum[c * 256 + b] = sh[255];
}

__global__ __launch_bounds__(256) void scan_b_kernel(int* bsum) {
  int c = blockIdx.x;
  int tid = threadIdx.x;
  int val = (tid < SCAN_B) ? bsum[c * 256 + tid] : 0;
  __shared__ int sh[256];
  sh[tid] = val;
  __syncthreads();
  for (int off = 1; off < 256; off <<= 1) {
    int t = (tid >= off) ? sh[tid - off] : 0;
    __syncthreads();
    sh[tid] += t;
    __syncthreads();
  }
  bsum[c * 256 + tid] = sh[tid] - val;          // exclusive
}

__global__ __launch_bounds__(256) void scan_c_kernel(int* rowptr, const int* __restrict__ bsum) {
  int c = blockIdx.x / SCAN_B;
  int b = blockIdx.x - c * SCAN_B;
  int i = b * 256 + threadIdx.x;
  if (i < NN) rowptr[c * (NN + 1) + i + 1] += bsum[c * 256 + b];
  if (i == 0) rowptr[c * (NN + 1)] = 0;
}

// fill: atomic-free. slot = rowptr[d] + pos[e]; one 8B scattered write.
__global__ __launch_bounds__(256) void fill_kernel(const int* __restrict__ ei,
                                                   const float* __restrict__ ew,
                                                   const float* __restrict__ dis,
                                                   const int* __restrict__ rowptr,
                                                   const int* __restrict__ pos,
                                                   int2* __restrict__ csr) {
  int stride = gridDim.x * 256;
  for (int idx = blockIdx.x * 256 + threadIdx.x; idx < CE; idx += stride) {
    int c = idx / EE, e = idx - c * EE;
    int s = ei[(c * 2 + 0) * EE + e];
    int d = ei[(c * 2 + 1) * EE + e];
    float w = ew[idx];
    float nrm = dis[c * NN + s] * w * dis[c * NN + d];
    int slot = rowptr[c * (NN + 1) + d] + pos[idx];
    csr[c * EE + slot] = make_int2(s, __float_as_int(nrm));
  }
}

// ---------------------------------------------------------------------------
// fp32 GEMM (relation-batched): h[c][r][NC] = A[c][r][128] @ B[c][128][NC].
// Grid = nRel * BLK_GEMM_REL blocks; B of one relation fully LDS-resident.
// ---------------------------------------------------------------------------

template <int NC>
__global__ __launch_bounds__(256) void gemm_kernel(const float* __restrict__ A,
                                                   const float* __restrict__ B,
                                                   float* __restrict__ Cout) {
  constexpr int K = 128;
  constexpr int KC = 32;
  constexpr int CPT = NC / 32;                   // cols per thread: 4 or 2
  __shared__ float Bs[K * NC];
  __shared__ float As[64][KC + 4];

  int c  = blockIdx.x / BLK_GEMM_REL;
  int bl = blockIdx.x - c * BLK_GEMM_REL;
  const float* Bc = B + (size_t)c * K * NC;
  const float* Ac = A + (size_t)c * NN * K;
  float* Cc = Cout + (size_t)c * NN * NC;

  int tid = threadIdx.x;
  {
    const float4* B4 = (const float4*)Bc;
    float4* Bs4 = (float4*)Bs;
    for (int i = tid; i < K * NC / 4; i += 256) Bs4[i] = B4[i];
  }
  int tx = tid & 31;
  int ty = tid >> 5;
  int rowBase = bl * 64;

  float acc[8][CPT];
#pragma unroll
  for (int i = 0; i < 8; ++i)
#pragma unroll
    for (int j = 0; j < CPT; ++j) acc[i][j] = 0.f;

  for (int kc = 0; kc < K; kc += KC) {
    __syncthreads();
    int lr = tid >> 3;
    int lc = (tid & 7) * 4;
#pragma unroll
    for (int rr = 0; rr < 64; rr += 32) {
      int r = lr + rr;
      int gr = rowBase + r;
      float4 v = make_float4(0.f, 0.f, 0.f, 0.f);
      if (gr < NN) v = *(const float4*)&Ac[(size_t)gr * K + kc + lc];
      *(float4*)&As[r][lc] = v;
    }
    __syncthreads();

#pragma unroll
    for (int kk = 0; kk < KC; kk += 4) {
      float4 av[8];
#pragma unroll
      for (int i = 0; i < 8; ++i) av[i] = *(const float4*)&As[ty * 8 + i][kk];
#pragma unroll
      for (int u = 0; u < 4; ++u) {
        int k = kc + kk + u;
        if constexpr (CPT == 4) {
          float4 bv = *(const float4*)&Bs[k * NC + tx * 4];
#pragma unroll
          for (int i = 0; i < 8; ++i) {
            float a = ((const float*)&av[i])[u];
            acc[i][0] += a * bv.x;
            acc[i][1] += a * bv.y;
            acc[i][2] += a * bv.z;
            acc[i][3] += a * bv.w;
          }
        } else {
          float2 bv = *(const float2*)&Bs[k * NC + tx * 2];
#pragma unroll
          for (int i = 0; i < 8; ++i) {
            float a = ((const float*)&av[i])[u];
            acc[i][0] += a * bv.x;
            acc[i][1] += a * bv.y;
          }
        }
      }
    }
  }

#pragma unroll
  for (int i = 0; i < 8; ++i) {
    int gr = rowBase + ty * 8 + i;
    if (gr >= NN) continue;
    if constexpr (CPT == 4) {
      *(float4*)&Cc[(size_t)gr * NC + tx * 4] =
          make_float4(acc[i][0], acc[i][1], acc[i][2], acc[i][3]);
    } else {
      *(float2*)&Cc[(size_t)gr * NC + tx * 2] = make_float2(acc[i][0], acc[i][1]);
    }
  }
}

// ---------------------------------------------------------------------------
// CSR aggregation (relation-batched): one wave per node.
// acc = bias + dis^2*h[n] + sum norm*h[src]. Grid = nRel * BLK_AGG_REL.
// ---------------------------------------------------------------------------

template <int F, bool RELU>
__global__ __launch_bounds__(256) void agg_kernel(const float* __restrict__ h,
                                                  const int* __restrict__ rowptr,
                                                  const int2* __restrict__ csr,
                                                  const float* __restrict__ dis,
                                                  const float* __restrict__ bias,
                                                  float* __restrict__ out) {
  int c  = blockIdx.x / BLK_AGG_REL;
  int bl = blockIdx.x - c * BLK_AGG_REL;
  int node = bl * 4 + (threadIdx.x >> 6);
  int lane = threadIdx.x & 63;
  if (node >= NN) return;

  const float* hc = h + (size_t)c * NN * F;
  const int2* csrc = csr + (size_t)c * EE;
  float dn = dis[c * NN + node];
  float sn = dn * dn;   // self-loop norm = dis*1*dis
  int beg = rowptr[c * (NN + 1) + node];
  int end = rowptr[c * (NN + 1) + node + 1];

  if constexpr (F == 128) {
    int f = lane * 2;
    float a0 = bias[c * F + f], a1 = bias[c * F + f + 1];
    float2 hv = *(const float2*)&hc[(size_t)node * F + f];
    a0 += sn * hv.x;
    a1 += sn * hv.y;
    for (int idx = beg; idx < end; ++idx) {
      int2 en = csrc[idx];
      float nm = __int_as_float(en.y);
      float2 v = *(const float2*)&hc[(size_t)en.x * F + f];
      a0 += nm * v.x;
      a1 += nm * v.y;
    }
    if (RELU) { a0 = fmaxf(a0, 0.f); a1 = fmaxf(a1, 0.f); }
    *(float2*)&out[((size_t)c * NN + node) * F + f] = make_float2(a0, a1);
  } else {
    int f = lane;
    float a0 = bias[c * F + f] + sn * hc[(size_t)node * F + f];
    for (int idx = beg; idx < end; ++idx) {
      int2 en = csrc[idx];
      a0 += __int_as_float(en.y) * hc[(size_t)en.x * F + f];
    }
    if (RELU) a0 = fmaxf(a0, 0.f);
    out[((size_t)c * NN + node) * F + f] = a0;
  }
}

// ---------------------------------------------------------------------------
// Host launcher
// ---------------------------------------------------------------------------

extern "C" void kernel_launch(void* const* d_in, const int* in_sizes, int n_in,
                              void* d_out, int out_size, void* d_ws, size_t ws_size,
                              hipStream_t stream) {
  const float* x  = (const float*)d_in[0];   // [C][N][128]
  const int*   ei = (const int*)d_in[1];     // [C][2][E]
  const float* ew = (const float*)d_in[2];   // [C][E]
  const float* W1 = (const float*)d_in[3];   // [C][128][128]
  const float* b1 = (const float*)d_in[4];   // [C][128]
  const float* W2 = (const float*)d_in[5];   // [C][128][64]
  const float* b2 = (const float*)d_in[6];   // [C][64]
  float* out = (float*)d_out;                // [C][N][64]

  char* ws = (char*)d_ws;
  size_t off = 0;
  auto alloc = [&](size_t bytes) {
    size_t cur = off;
    off += (bytes + 255) & ~(size_t)255;
    return cur;
  };
  unsigned long long* packed = (unsigned long long*)(ws + alloc((size_t)CN * 8));
  float* dis      = (float*)(ws + alloc((size_t)CN * 4));
  int*   rowptr   = (int*)  (ws + alloc((size_t)C_REL * (NN + 1) * 4));
  int*   bsum     = (int*)  (ws + alloc((size_t)C_REL * 256 * 4));
  int2*  csr      = (int2*) (ws + alloc((size_t)CE * 8));
  size_t fixed_end = off;

  const int NB_CN = (CN + 255) / 256;
  const int NB_EDGE = 4096;                  // grid-stride for edge kernels

  // Common prep (all relations batched)
  init_kernel<<<NB_CN, 256, 0, stream>>>(packed);

  // Decide batched vs sequential based on workspace size.
  size_t need_batched = fixed_end + 2 * (((size_t)CN * D_H * 4 + 255) & ~(size_t)255);
  bool batched = (ws_size >= need_batched);

  if (batched) {
    float* h1   = (float*)(ws + fixed_end);                         // [CN][128]
    float* agg1 = (float*)((char*)h1 + (((size_t)CN * D_H * 4 + 255) & ~(size_t)255));
    int* pos = (int*)h1;  // pos[CE]=16MB unions with h1 (dead before gemm1)

    hist_kernel<<<NB_EDGE, 256, 0, stream>>>(ei, ew, packed, pos);
    dis_kernel<<<NB_CN, 256, 0, stream>>>(packed, dis);
    scan_a_kernel<<<C_REL * SCAN_B, 256, 0, stream>>>(packed, rowptr, bsum);
    scan_b_kernel<<<C_REL, 256, 0, stream>>>(bsum);
    scan_c_kernel<<<C_REL * SCAN_B, 256, 0, stream>>>(rowptr, bsum);
    fill_kernel<<<NB_EDGE, 256, 0, stream>>>(ei, ew, dis, rowptr, pos, csr);

    // Layer 1 (all relations)
    gemm_kernel<D_H><<<C_REL * BLK_GEMM_REL, 256, 0, stream>>>(x, W1, h1);
    agg_kernel<D_H, true><<<C_REL * BLK_AGG_REL, 256, 0, stream>>>(h1, rowptr, csr, dis, b1, agg1);
    // Layer 2 (all relations); h2 reuses h1 buffer
    gemm_kernel<D_OUT><<<C_REL * BLK_GEMM_REL, 256, 0, stream>>>(agg1, W2, h1);
    agg_kernel<D_OUT, false><<<C_REL * BLK_AGG_REL, 256, 0, stream>>>(h1, rowptr, csr, dis, b2, out);
  } else {
    // Sequential fallback (~88MB): per-relation ping-pong buffers.
    float* h1   = (float*)(ws + fixed_end);                         // [NN][128]
    float* agg1 = (float*)((char*)h1 + (((size_t)NN * D_H * 4 + 255) & ~(size_t)255));
    int* pos = (int*)h1;

    hist_kernel<<<NB_EDGE, 256, 0, stream>>>(ei, ew, packed, pos);
    dis_kernel<<<NB_CN, 256, 0, stream>>>(packed, dis);
    scan_a_kernel<<<C_REL * SCAN_B, 256, 0, stream>>>(packed, rowptr, bsum);
    scan_b_kernel<<<C_REL, 256, 0, stream>>>(bsum);
    scan_c_kernel<<<C_REL * SCAN_B, 256, 0, stream>>>(rowptr, bsum);
    fill_kernel<<<NB_EDGE, 256, 0, stream>>>(ei, ew, dis, rowptr, pos, csr);

    for (int c = 0; c < C_REL; ++c) {
      const float* xc   = x  + (size_t)c * NN * D_IN;
      const float* W1c  = W1 + (size_t)c * D_IN * D_H;
      const float* b1c  = b1 + (size_t)c * D_H;
      const float* W2c  = W2 + (size_t)c * D_H * D_OUT;
      const float* b2c  = b2 + (size_t)c * D_OUT;
      const int*   rpc  = rowptr + (size_t)c * (NN + 1);
      const int2*  csc  = csr + (size_t)c * EE;
      const float* disc = dis + (size_t)c * NN;
      float* outc = out + (size_t)c * NN * D_OUT;

      gemm_kernel<D_H><<<BLK_GEMM_REL, 256, 0, stream>>>(xc, W1c, h1);
      agg_kernel<D_H, true><<<BLK_AGG_REL, 256, 0, stream>>>(h1, rpc, csc, disc, b1c, agg1);
      gemm_kernel<D_OUT><<<BLK_GEMM_REL, 256, 0, stream>>>(agg1, W2c, h1);
      agg_kernel<D_OUT, false><<<BLK_AGG_REL, 256, 0, stream>>>(h1, rpc, csc, disc, b2c, outc);
    }
  }
}

// Round 4
// 843.395 us; speedup vs baseline: 2.0806x; 1.6350x over previous
//
#include <hip/hip_runtime.h>
#include <hip/hip_fp16.h>

// Problem constants (from reference)
#define C_REL 5
#define NN    50000
#define EE    800000
#define D_IN  128
#define D_H   128
#define D_OUT 64

static constexpr int CN = C_REL * NN;            // 250000
static constexpr int CE = C_REL * EE;            // 4000000
static constexpr int SCAN_B = (NN + 255) / 256;  // 196 blocks per relation
static constexpr int BLK_GEMM_REL = (NN + 63) / 64;   // 782
static constexpr int BLK_AGG_REL  = NN / 4;           // 12500
static constexpr int FILL_BLOCKS  = 2048;
static constexpr int FUSED_GRID   = 6144;             // 3-way interleave: 2 gemm : 1 fill

static constexpr unsigned long long MASK40 = (1ULL << 40) - 1;
static constexpr float FIX_SCALE = 16777216.0f;       // 2^24
static constexpr float FIX_INV   = 1.0f / 16777216.0f;

__device__ inline unsigned pack2h(float a, float b) {
  __half2 h = __floats2half2_rn(a, b);
  return *reinterpret_cast<unsigned*>(&h);
}

// ---------------------------------------------------------------------------
// Prep: packed (cnt<<40 | fixpoint weight-sum) histogram, one atomic per edge.
// ---------------------------------------------------------------------------

__global__ __launch_bounds__(256) void init_kernel(unsigned long long* packed) {
  int i = blockIdx.x * 256 + threadIdx.x;
  if (i < CN) packed[i] = 0ULL;
}

__global__ __launch_bounds__(256) void hist_kernel(const int* __restrict__ ei,
                                                   const float* __restrict__ ew,
                                                   unsigned long long* packed,
                                                   int* __restrict__ pos) {
  int stride = gridDim.x * 256;
  for (int idx = blockIdx.x * 256 + threadIdx.x; idx < CE; idx += stride) {
    int c = idx / EE, e = idx - c * EE;
    int d = ei[(c * 2 + 1) * EE + e];
    float w = ew[idx];
    unsigned long long wfix = (unsigned long long)(w * FIX_SCALE + 0.5f);
    unsigned long long old = atomicAdd(&packed[c * NN + d], (1ULL << 40) | wfix);
    pos[idx] = (int)(old >> 40);
  }
}

__global__ __launch_bounds__(256) void dis_kernel(const unsigned long long* __restrict__ packed,
                                                  float* __restrict__ dis) {
  int i = blockIdx.x * 256 + threadIdx.x;
  if (i >= CN) return;
  float deg = 1.0f + (float)(packed[i] & MASK40) * FIX_INV;  // self-loop w=1
  dis[i] = rsqrtf(deg);
}

__global__ __launch_bounds__(256) void scan_a_kernel(const unsigned long long* __restrict__ packed,
                                                     int* rowptr, int* bsum) {
  int c = blockIdx.x / SCAN_B;
  int b = blockIdx.x - c * SCAN_B;
  int tid = threadIdx.x;
  int i = b * 256 + tid;
  int val = (i < NN) ? (int)(packed[c * NN + i] >> 40) : 0;
  __shared__ int sh[256];
  sh[tid] = val;
  __syncthreads();
  for (int off = 1; off < 256; off <<= 1) {
    int t = (tid >= off) ? sh[tid - off] : 0;
    __syncthreads();
    sh[tid] += t;
    __syncthreads();
  }
  if (i < NN) rowptr[c * (NN + 1) + i + 1] = sh[tid];
  if (tid == 255) bsum[c * 256 + b] = sh[255];
}

__global__ __launch_bounds__(256) void scan_b_kernel(int* bsum) {
  int c = blockIdx.x;
  int tid = threadIdx.x;
  int val = (tid < SCAN_B) ? bsum[c * 256 + tid] : 0;
  __shared__ int sh[256];
  sh[tid] = val;
  __syncthreads();
  for (int off = 1; off < 256; off <<= 1) {
    int t = (tid >= off) ? sh[tid - off] : 0;
    __syncthreads();
    sh[tid] += t;
    __syncthreads();
  }
  bsum[c * 256 + tid] = sh[tid] - val;          // exclusive
}

__global__ __launch_bounds__(256) void scan_c_kernel(int* rowptr, const int* __restrict__ bsum) {
  int c = blockIdx.x / SCAN_B;
  int b = blockIdx.x - c * SCAN_B;
  int i = b * 256 + threadIdx.x;
  if (i < NN) rowptr[c * (NN + 1) + i + 1] += bsum[c * 256 + b];
  if (i == 0) rowptr[c * (NN + 1)] = 0;
}

// ---------------------------------------------------------------------------
// fill body: atomic-free; csr entry = src:16 | half(norm):16 (4B scattered write)
// ---------------------------------------------------------------------------

__device__ inline void fill_body(int bid, int nblocks,
                                 const int* __restrict__ ei,
                                 const float* __restrict__ ew,
                                 const float* __restrict__ dis,
                                 const int* __restrict__ rowptr,
                                 const int* __restrict__ pos,
                                 unsigned* __restrict__ csr) {
  int stride = nblocks * 256;
  for (int idx = bid * 256 + threadIdx.x; idx < CE; idx += stride) {
    int c = idx / EE, e = idx - c * EE;
    int s = ei[(c * 2 + 0) * EE + e];
    int d = ei[(c * 2 + 1) * EE + e];
    float w = ew[idx];
    float nrm = dis[c * NN + s] * w * dis[c * NN + d];
    int slot = rowptr[c * (NN + 1) + d] + pos[idx];
    unsigned ent = (unsigned)s | ((unsigned)__half_as_ushort(__float2half_rn(nrm)) << 16);
    csr[(size_t)c * EE + slot] = ent;
  }
}

// ---------------------------------------------------------------------------
// fp32 GEMM body (relation-batched), fp16 output.
// bid in [0, C_REL*BLK_GEMM_REL). B of one relation fully LDS-resident.
// ---------------------------------------------------------------------------

template <int NC>
__device__ inline void gemm_body(int bid, const float* __restrict__ A,
                                 const float* __restrict__ B,
                                 __half* __restrict__ Cout) {
  constexpr int K = 128;
  constexpr int KC = 32;
  constexpr int CPT = NC / 32;                   // cols per thread: 4 or 2
  __shared__ float Bs[K * NC];
  __shared__ float As[64][KC + 4];

  int c  = bid / BLK_GEMM_REL;
  int bl = bid - c * BLK_GEMM_REL;
  const float* Bc = B + (size_t)c * K * NC;
  const float* Ac = A + (size_t)c * NN * K;
  __half* Cc = Cout + (size_t)c * NN * NC;

  int tid = threadIdx.x;
  {
    const float4* B4 = (const float4*)Bc;
    float4* Bs4 = (float4*)Bs;
    for (int i = tid; i < K * NC / 4; i += 256) Bs4[i] = B4[i];
  }
  int tx = tid & 31;
  int ty = tid >> 5;
  int rowBase = bl * 64;

  float acc[8][CPT];
#pragma unroll
  for (int i = 0; i < 8; ++i)
#pragma unroll
    for (int j = 0; j < CPT; ++j) acc[i][j] = 0.f;

  for (int kc = 0; kc < K; kc += KC) {
    __syncthreads();
    int lr = tid >> 3;
    int lc = (tid & 7) * 4;
#pragma unroll
    for (int rr = 0; rr < 64; rr += 32) {
      int r = lr + rr;
      int gr = rowBase + r;
      float4 v = make_float4(0.f, 0.f, 0.f, 0.f);
      if (gr < NN) v = *(const float4*)&Ac[(size_t)gr * K + kc + lc];
      *(float4*)&As[r][lc] = v;
    }
    __syncthreads();

#pragma unroll
    for (int kk = 0; kk < KC; kk += 4) {
      float4 av[8];
#pragma unroll
      for (int i = 0; i < 8; ++i) av[i] = *(const float4*)&As[ty * 8 + i][kk];
#pragma unroll
      for (int u = 0; u < 4; ++u) {
        int k = kc + kk + u;
        if constexpr (CPT == 4) {
          float4 bv = *(const float4*)&Bs[k * NC + tx * 4];
#pragma unroll
          for (int i = 0; i < 8; ++i) {
            float a = ((const float*)&av[i])[u];
            acc[i][0] += a * bv.x;
            acc[i][1] += a * bv.y;
            acc[i][2] += a * bv.z;
            acc[i][3] += a * bv.w;
          }
        } else {
          float2 bv = *(const float2*)&Bs[k * NC + tx * 2];
#pragma unroll
          for (int i = 0; i < 8; ++i) {
            float a = ((const float*)&av[i])[u];
            acc[i][0] += a * bv.x;
            acc[i][1] += a * bv.y;
          }
        }
      }
    }
  }

#pragma unroll
  for (int i = 0; i < 8; ++i) {
    int gr = rowBase + ty * 8 + i;
    if (gr >= NN) continue;
    if constexpr (CPT == 4) {
      unsigned lo = pack2h(acc[i][0], acc[i][1]);
      unsigned hi = pack2h(acc[i][2], acc[i][3]);
      *(uint2*)&Cc[(size_t)gr * NC + tx * 4] = make_uint2(lo, hi);
    } else {
      *(unsigned*)&Cc[(size_t)gr * NC + tx * 2] = pack2h(acc[i][0], acc[i][1]);
    }
  }
}

// Fused: gemm1 (x@W1 -> h1 fp16) interleaved with fill (CSR build).
// Roles interleaved 2:1 so both are co-resident from dispatch start.
__global__ __launch_bounds__(256) void fused_gemm1_fill_kernel(
    const float* __restrict__ x, const float* __restrict__ W1, __half* __restrict__ h1,
    const int* __restrict__ ei, const float* __restrict__ ew,
    const float* __restrict__ dis, const int* __restrict__ rowptr,
    const int* __restrict__ pos, unsigned* __restrict__ csr) {
  int id = blockIdx.x;
  int r = id % 3;
  if (r < 2) {
    int gid = (id / 3) * 2 + r;
    if (gid < C_REL * BLK_GEMM_REL) gemm_body<D_H>(gid, x, W1, h1);
  } else {
    fill_body(id / 3, FILL_BLOCKS, ei, ew, dis, rowptr, pos, csr);
  }
}

__global__ __launch_bounds__(256) void gemm2_kernel(const float* __restrict__ A,
                                                    const float* __restrict__ B,
                                                    __half* __restrict__ Cout) {
  gemm_body<D_OUT>(blockIdx.x, A, B, Cout);
}

// ---------------------------------------------------------------------------
// agg1: F=128, one wave per node, fp16 gathers (half2/lane), unroll-4.
// out = relu(bias + dis^2*h[n] + sum norm*h[src])  (fp32 out, layer-2 GEMM input)
// ---------------------------------------------------------------------------

__global__ __launch_bounds__(256) void agg1_kernel(const __half2* __restrict__ h,
                                                   const int* __restrict__ rowptr,
                                                   const unsigned* __restrict__ csr,
                                                   const float* __restrict__ dis,
                                                   const float* __restrict__ bias,
                                                   float* __restrict__ out) {
  int c  = blockIdx.x / BLK_AGG_REL;
  int bl = blockIdx.x - c * BLK_AGG_REL;
  int node = bl * 4 + (threadIdx.x >> 6);
  int lane = threadIdx.x & 63;

  const __half2* hc = h + (size_t)c * NN * 64;       // row = 64 half2
  const unsigned* csrc = csr + (size_t)c * EE;
  int beg = rowptr[c * (NN + 1) + node];
  int end = rowptr[c * (NN + 1) + node + 1];

  float a0 = 0.f, a1 = 0.f;
  int idx = beg;
  for (; idx + 4 <= end; idx += 4) {
    unsigned e0 = csrc[idx], e1 = csrc[idx + 1], e2 = csrc[idx + 2], e3 = csrc[idx + 3];
    float2 v0 = __half22float2(hc[(size_t)(e0 & 0xffffu) * 64 + lane]);
    float2 v1 = __half22float2(hc[(size_t)(e1 & 0xffffu) * 64 + lane]);
    float2 v2 = __half22float2(hc[(size_t)(e2 & 0xffffu) * 64 + lane]);
    float2 v3 = __half22float2(hc[(size_t)(e3 & 0xffffu) * 64 + lane]);
    float n0 = __half2float(__ushort_as_half((unsigned short)(e0 >> 16)));
    float n1 = __half2float(__ushort_as_half((unsigned short)(e1 >> 16)));
    float n2 = __half2float(__ushort_as_half((unsigned short)(e2 >> 16)));
    float n3 = __half2float(__ushort_as_half((unsigned short)(e3 >> 16)));
    a0 += n0 * v0.x + n1 * v1.x + n2 * v2.x + n3 * v3.x;
    a1 += n0 * v0.y + n1 * v1.y + n2 * v2.y + n3 * v3.y;
  }
  for (; idx < end; ++idx) {
    unsigned e = csrc[idx];
    float2 v = __half22float2(hc[(size_t)(e & 0xffffu) * 64 + lane]);
    float nm = __half2float(__ushort_as_half((unsigned short)(e >> 16)));
    a0 += nm * v.x;
    a1 += nm * v.y;
  }
  float dn = dis[c * NN + node];
  float sn = dn * dn;                                 // self-loop norm
  float2 hv = __half22float2(hc[(size_t)node * 64 + lane]);
  int f = lane * 2;
  a0 += sn * hv.x + bias[c * 128 + f];
  a1 += sn * hv.y + bias[c * 128 + f + 1];
  a0 = fmaxf(a0, 0.f);
  a1 = fmaxf(a1, 0.f);
  *(float2*)&out[((size_t)c * NN + node) * 128 + f] = make_float2(a0, a1);
}

// ---------------------------------------------------------------------------
// agg2: F=64, one wave per node, half-wave edge split (lanes 0-31 even edges,
// 32-63 odd edges), __shfl_xor(32) combine. fp32 final output.
// ---------------------------------------------------------------------------

__global__ __launch_bounds__(256) void agg2_kernel(const __half2* __restrict__ h,
                                                   const int* __restrict__ rowptr,
                                                   const unsigned* __restrict__ csr,
                                                   const float* __restrict__ dis,
                                                   const float* __restrict__ bias,
                                                   float* __restrict__ out) {
  int c  = blockIdx.x / BLK_AGG_REL;
  int bl = blockIdx.x - c * BLK_AGG_REL;
  int node = bl * 4 + (threadIdx.x >> 6);
  int lane = threadIdx.x & 63;
  int hf = lane >> 5;       // which half-wave
  int fl = lane & 31;       // feature-pair index

  const __half2* hc = h + (size_t)c * NN * 32;       // row = 32 half2
  const unsigned* csrc = csr + (size_t)c * EE;
  int beg = rowptr[c * (NN + 1) + node];
  int end = rowptr[c * (NN + 1) + node + 1];

  float a0 = 0.f, a1 = 0.f;
  int idx = beg + hf;
  for (; idx + 2 < end; idx += 4) {     // 2 edges per half per iter
    unsigned ea = csrc[idx], eb = csrc[idx + 2];
    float2 va = __half22float2(hc[(size_t)(ea & 0xffffu) * 32 + fl]);
    float2 vb = __half22float2(hc[(size_t)(eb & 0xffffu) * 32 + fl]);
    float na = __half2float(__ushort_as_half((unsigned short)(ea >> 16)));
    float nb = __half2float(__ushort_as_half((unsigned short)(eb >> 16)));
    a0 += na * va.x + nb * vb.x;
    a1 += na * va.y + nb * vb.y;
  }
  for (; idx < end; idx += 2) {
    unsigned e = csrc[idx];
    float2 v = __half22float2(hc[(size_t)(e & 0xffffu) * 32 + fl]);
    float nm = __half2float(__ushort_as_half((unsigned short)(e >> 16)));
    a0 += nm * v.x;
    a1 += nm * v.y;
  }
  a0 += __shfl_xor(a0, 32, 64);
  a1 += __shfl_xor(a1, 32, 64);
  if (hf == 0) {
    float dn = dis[c * NN + node];
    float sn = dn * dn;
    float2 hv = __half22float2(hc[(size_t)node * 32 + fl]);
    int f = fl * 2;
    a0 += sn * hv.x + bias[c * 64 + f];
    a1 += sn * hv.y + bias[c * 64 + f + 1];
    *(float2*)&out[((size_t)c * NN + node) * 64 + f] = make_float2(a0, a1);
  }
}

// ---------------------------------------------------------------------------
// Host launcher
// ---------------------------------------------------------------------------

extern "C" void kernel_launch(void* const* d_in, const int* in_sizes, int n_in,
                              void* d_out, int out_size, void* d_ws, size_t ws_size,
                              hipStream_t stream) {
  const float* x  = (const float*)d_in[0];   // [C][N][128]
  const int*   ei = (const int*)d_in[1];     // [C][2][E]
  const float* ew = (const float*)d_in[2];   // [C][E]
  const float* W1 = (const float*)d_in[3];   // [C][128][128]
  const float* b1 = (const float*)d_in[4];   // [C][128]
  const float* W2 = (const float*)d_in[5];   // [C][128][64]
  const float* b2 = (const float*)d_in[6];   // [C][64]
  float* out = (float*)d_out;                // [C][N][64]

  char* ws = (char*)d_ws;
  size_t off = 0;
  auto alloc = [&](size_t bytes) {
    size_t cur = off;
    off += (bytes + 255) & ~(size_t)255;
    return cur;
  };
  unsigned long long* packed = (unsigned long long*)(ws + alloc((size_t)CN * 8));
  float*    dis    = (float*)   (ws + alloc((size_t)CN * 4));
  int*      rowptr = (int*)     (ws + alloc((size_t)C_REL * (NN + 1) * 4));
  int*      bsum   = (int*)     (ws + alloc((size_t)C_REL * 256 * 4));
  unsigned* csr    = (unsigned*)(ws + alloc((size_t)CE * 4));
  __half*   h1     = (__half*)  (ws + alloc((size_t)CN * D_H * 2));   // h1/h2 (fp16)
  float*    agg1   = (float*)   (ws + alloc((size_t)CN * D_H * 4));   // relu output (fp32)
  // pos[CE] (16MB) unions with agg1 (128MB): pos is dead before agg1_kernel runs.
  int* pos = (int*)agg1;

  const int NB_CN = (CN + 255) / 256;

  init_kernel<<<NB_CN, 256, 0, stream>>>(packed);
  hist_kernel<<<4096, 256, 0, stream>>>(ei, ew, packed, pos);
  dis_kernel<<<NB_CN, 256, 0, stream>>>(packed, dis);
  scan_a_kernel<<<C_REL * SCAN_B, 256, 0, stream>>>(packed, rowptr, bsum);
  scan_b_kernel<<<C_REL, 256, 0, stream>>>(bsum);
  scan_c_kernel<<<C_REL * SCAN_B, 256, 0, stream>>>(rowptr, bsum);

  // gemm1 (VALU-heavy) runs concurrently with fill (scatter-write-heavy).
  fused_gemm1_fill_kernel<<<FUSED_GRID, 256, 0, stream>>>(x, W1, h1, ei, ew, dis,
                                                          rowptr, pos, csr);

  agg1_kernel<<<C_REL * BLK_AGG_REL, 256, 0, stream>>>((const __half2*)h1, rowptr, csr,
                                                       dis, b1, agg1);
  gemm2_kernel<<<C_REL * BLK_GEMM_REL, 256, 0, stream>>>(agg1, W2, h1);
  agg2_kernel<<<C_REL * BLK_AGG_REL, 256, 0, stream>>>((const __half2*)h1, rowptr, csr,
                                                       dis, b2, out);
}

// Round 5
// 726.342 us; speedup vs baseline: 2.4159x; 1.1612x over previous
//
#include <hip/hip_runtime.h>
#include <hip/hip_fp16.h>

// Problem constants (from reference)
#define C_REL 5
#define NN    50000
#define EE    800000
#define D_IN  128
#define D_H   128
#define D_OUT 64

static constexpr int CN = C_REL * NN;            // 250000
static constexpr int CE = C_REL * EE;            // 4000000
static constexpr int SCAN_B = (NN + 255) / 256;  // 196 blocks per relation
static constexpr int BLK_GEMM_REL = (NN + 63) / 64;   // 782
static constexpr int BLK_AGG_REL  = NN / 4;           // 12500
static constexpr int GEMM_BLOCKS  = C_REL * BLK_GEMM_REL; // 3910
static constexpr int HIST_BLOCKS  = 4096;
static constexpr int FUSED_GRID   = 2 * HIST_BLOCKS;      // 8192, 1:1 interleave
static constexpr int FILL_BLOCKS  = 4096;

static constexpr unsigned long long MASK40 = (1ULL << 40) - 1;
static constexpr float FIX_SCALE = 16777216.0f;       // 2^24
static constexpr float FIX_INV   = 1.0f / 16777216.0f;

__device__ inline unsigned pack2h(float a, float b) {
  __half2 h = __floats2half2_rn(a, b);
  return *reinterpret_cast<unsigned*>(&h);
}

// ---------------------------------------------------------------------------
// Prep bodies
// ---------------------------------------------------------------------------

__global__ __launch_bounds__(256) void init_kernel(unsigned long long* packed) {
  int i = blockIdx.x * 256 + threadIdx.x;
  if (i < CN) packed[i] = 0ULL;
}

__device__ inline void hist_body(int bid, int nblocks,
                                 const int* __restrict__ ei,
                                 const float* __restrict__ ew,
                                 unsigned long long* packed,
                                 int* __restrict__ pos) {
  int stride = nblocks * 256;
  for (int idx = bid * 256 + threadIdx.x; idx < CE; idx += stride) {
    int c = idx / EE, e = idx - c * EE;
    int d = ei[(c * 2 + 1) * EE + e];
    float w = ew[idx];
    unsigned long long wfix = (unsigned long long)(w * FIX_SCALE + 0.5f);
    unsigned long long old = atomicAdd(&packed[c * NN + d], (1ULL << 40) | wfix);
    pos[idx] = (int)(old >> 40);
  }
}

__global__ __launch_bounds__(256) void dis_kernel(const unsigned long long* __restrict__ packed,
                                                  float* __restrict__ dis) {
  int i = blockIdx.x * 256 + threadIdx.x;
  if (i >= CN) return;
  float deg = 1.0f + (float)(packed[i] & MASK40) * FIX_INV;  // self-loop w=1
  dis[i] = rsqrtf(deg);
}

__global__ __launch_bounds__(256) void scan_a_kernel(const unsigned long long* __restrict__ packed,
                                                     int* rowptr, int* bsum) {
  int c = blockIdx.x / SCAN_B;
  int b = blockIdx.x - c * SCAN_B;
  int tid = threadIdx.x;
  int i = b * 256 + tid;
  int val = (i < NN) ? (int)(packed[c * NN + i] >> 40) : 0;
  __shared__ int sh[256];
  sh[tid] = val;
  __syncthreads();
  for (int off = 1; off < 256; off <<= 1) {
    int t = (tid >= off) ? sh[tid - off] : 0;
    __syncthreads();
    sh[tid] += t;
    __syncthreads();
  }
  if (i < NN) rowptr[c * (NN + 1) + i + 1] = sh[tid];
  if (tid == 255) bsum[c * 256 + b] = sh[255];
}

__global__ __launch_bounds__(256) void scan_b_kernel(int* bsum) {
  int c = blockIdx.x;
  int tid = threadIdx.x;
  int val = (tid < SCAN_B) ? bsum[c * 256 + tid] : 0;
  __shared__ int sh[256];
  sh[tid] = val;
  __syncthreads();
  for (int off = 1; off < 256; off <<= 1) {
    int t = (tid >= off) ? sh[tid - off] : 0;
    __syncthreads();
    sh[tid] += t;
    __syncthreads();
  }
  bsum[c * 256 + tid] = sh[tid] - val;          // exclusive
}

__global__ __launch_bounds__(256) void scan_c_kernel(int* rowptr, const int* __restrict__ bsum) {
  int c = blockIdx.x / SCAN_B;
  int b = blockIdx.x - c * SCAN_B;
  int i = b * 256 + threadIdx.x;
  if (i < NN) rowptr[c * (NN + 1) + i + 1] += bsum[c * 256 + b];
  if (i == 0) rowptr[c * (NN + 1)] = 0;
}

// fill: atomic-free; csr entry = src:16 | half(norm):16 (4B scattered write)
__global__ __launch_bounds__(256) void fill_kernel(const int* __restrict__ ei,
                                                   const float* __restrict__ ew,
                                                   const float* __restrict__ dis,
                                                   const int* __restrict__ rowptr,
                                                   const int* __restrict__ pos,
                                                   unsigned* __restrict__ csr) {
  int stride = gridDim.x * 256;
  for (int idx = blockIdx.x * 256 + threadIdx.x; idx < CE; idx += stride) {
    int c = idx / EE, e = idx - c * EE;
    int s = ei[(c * 2 + 0) * EE + e];
    int d = ei[(c * 2 + 1) * EE + e];
    float w = ew[idx];
    float nrm = dis[c * NN + s] * w * dis[c * NN + d];
    int slot = rowptr[c * (NN + 1) + d] + pos[idx];
    unsigned ent = (unsigned)s | ((unsigned)__half_as_ushort(__float2half_rn(nrm)) << 16);
    csr[(size_t)c * EE + slot] = ent;
  }
}

// ---------------------------------------------------------------------------
// GEMM body (relation-batched): C[c] = A[c] @ B[c], fp32 math, fp16 output.
// B staged per-K-chunk (Bs[32][NC], 16KB/8KB) so LDS ~25KB -> 6 blocks/CU.
// AHALF: A is fp16 (converted to fp32 during LDS staging).
// ---------------------------------------------------------------------------

template <int NC, bool AHALF>
__device__ inline void gemm_body(int bid, const void* __restrict__ Av,
                                 const float* __restrict__ B,
                                 __half* __restrict__ Cout) {
  constexpr int K = 128;
  constexpr int KC = 32;
  constexpr int CPT = NC / 32;                   // cols per thread: 4 or 2
  __shared__ float Bs[KC * NC];                  // 16KB (NC=128) / 8KB (NC=64)
  __shared__ float As[64][KC + 4];               // 9216B

  int c  = bid / BLK_GEMM_REL;
  int bl = bid - c * BLK_GEMM_REL;
  const float* Bc = B + (size_t)c * K * NC;
  __half* Cc = Cout + (size_t)c * NN * NC;

  int tid = threadIdx.x;
  int tx = tid & 31;
  int ty = tid >> 5;
  int rowBase = bl * 64;

  float acc[8][CPT];
#pragma unroll
  for (int i = 0; i < 8; ++i)
#pragma unroll
    for (int j = 0; j < CPT; ++j) acc[i][j] = 0.f;

  for (int kc = 0; kc < K; kc += KC) {
    __syncthreads();
    // Stage B chunk (contiguous KC*NC floats at kc*NC)
    {
      const float4* B4 = (const float4*)(Bc + (size_t)kc * NC);
      float4* Bs4 = (float4*)Bs;
#pragma unroll
      for (int i = tid; i < KC * NC / 4; i += 256) Bs4[i] = B4[i];
    }
    // Stage A tile [64][32]
    if constexpr (AHALF) {
      const __half* Ac = (const __half*)Av + (size_t)c * NN * K;
      int lr = tid >> 2;
      int lc = (tid & 3) * 8;
      int gr = rowBase + lr;
      uint4 v = make_uint4(0u, 0u, 0u, 0u);
      if (gr < NN) v = *(const uint4*)&Ac[(size_t)gr * K + kc + lc];
      const __half2* hp = (const __half2*)&v;
#pragma unroll
      for (int j = 0; j < 4; ++j) {
        float2 f = __half22float2(hp[j]);
        As[lr][lc + 2 * j]     = f.x;
        As[lr][lc + 2 * j + 1] = f.y;
      }
    } else {
      const float* Ac = (const float*)Av + (size_t)c * NN * K;
      int lr = tid >> 3;
      int lc = (tid & 7) * 4;
#pragma unroll
      for (int rr = 0; rr < 64; rr += 32) {
        int r = lr + rr;
        int gr = rowBase + r;
        float4 v = make_float4(0.f, 0.f, 0.f, 0.f);
        if (gr < NN) v = *(const float4*)&Ac[(size_t)gr * K + kc + lc];
        *(float4*)&As[r][lc] = v;
      }
    }
    __syncthreads();

#pragma unroll
    for (int kk = 0; kk < KC; kk += 4) {
      float4 av[8];
#pragma unroll
      for (int i = 0; i < 8; ++i) av[i] = *(const float4*)&As[ty * 8 + i][kk];
#pragma unroll
      for (int u = 0; u < 4; ++u) {
        int k = kk + u;
        if constexpr (CPT == 4) {
          float4 bv = *(const float4*)&Bs[k * NC + tx * 4];
#pragma unroll
          for (int i = 0; i < 8; ++i) {
            float a = ((const float*)&av[i])[u];
            acc[i][0] += a * bv.x;
            acc[i][1] += a * bv.y;
            acc[i][2] += a * bv.z;
            acc[i][3] += a * bv.w;
          }
        } else {
          float2 bv = *(const float2*)&Bs[k * NC + tx * 2];
#pragma unroll
          for (int i = 0; i < 8; ++i) {
            float a = ((const float*)&av[i])[u];
            acc[i][0] += a * bv.x;
            acc[i][1] += a * bv.y;
          }
        }
      }
    }
  }

#pragma unroll
  for (int i = 0; i < 8; ++i) {
    int gr = rowBase + ty * 8 + i;
    if (gr >= NN) continue;
    if constexpr (CPT == 4) {
      unsigned lo = pack2h(acc[i][0], acc[i][1]);
      unsigned hi = pack2h(acc[i][2], acc[i][3]);
      *(uint2*)&Cc[(size_t)gr * NC + tx * 4] = make_uint2(lo, hi);
    } else {
      *(unsigned*)&Cc[(size_t)gr * NC + tx * 2] = pack2h(acc[i][0], acc[i][1]);
    }
  }
}

// Fused: hist (atomic/L2-bound) || gemm1 (VALU-bound) - fully independent.
__global__ __launch_bounds__(256) void fused_hist_gemm1_kernel(
    const float* __restrict__ x, const float* __restrict__ W1, __half* __restrict__ h1,
    const int* __restrict__ ei, const float* __restrict__ ew,
    unsigned long long* packed, int* __restrict__ pos) {
  int id = blockIdx.x;
  if (id & 1) {
    hist_body(id >> 1, HIST_BLOCKS, ei, ew, packed, pos);
  } else {
    int gid = id >> 1;
    if (gid < GEMM_BLOCKS) gemm_body<D_H, false>(gid, x, W1, h1);
  }
}

__global__ __launch_bounds__(256) void gemm2_kernel(const __half* __restrict__ A,
                                                    const float* __restrict__ B,
                                                    __half* __restrict__ Cout) {
  gemm_body<D_OUT, true>(blockIdx.x, A, B, Cout);
}

// ---------------------------------------------------------------------------
// agg1: F=128, one wave per node, fp16 gathers (half2/lane), unroll-4.
// out = relu(bias + dis^2*h[n] + sum norm*h[src])  -> fp16 (feeds gemm2 only)
// ---------------------------------------------------------------------------

__global__ __launch_bounds__(256) void agg1_kernel(const __half2* __restrict__ h,
                                                   const int* __restrict__ rowptr,
                                                   const unsigned* __restrict__ csr,
                                                   const float* __restrict__ dis,
                                                   const float* __restrict__ bias,
                                                   __half* __restrict__ out) {
  int c  = blockIdx.x / BLK_AGG_REL;
  int bl = blockIdx.x - c * BLK_AGG_REL;
  int node = bl * 4 + (threadIdx.x >> 6);
  int lane = threadIdx.x & 63;

  const __half2* hc = h + (size_t)c * NN * 64;       // row = 64 half2
  const unsigned* csrc = csr + (size_t)c * EE;
  int beg = rowptr[c * (NN + 1) + node];
  int end = rowptr[c * (NN + 1) + node + 1];

  float a0 = 0.f, a1 = 0.f;
  int idx = beg;
  for (; idx + 4 <= end; idx += 4) {
    unsigned e0 = csrc[idx], e1 = csrc[idx + 1], e2 = csrc[idx + 2], e3 = csrc[idx + 3];
    float2 v0 = __half22float2(hc[(size_t)(e0 & 0xffffu) * 64 + lane]);
    float2 v1 = __half22float2(hc[(size_t)(e1 & 0xffffu) * 64 + lane]);
    float2 v2 = __half22float2(hc[(size_t)(e2 & 0xffffu) * 64 + lane]);
    float2 v3 = __half22float2(hc[(size_t)(e3 & 0xffffu) * 64 + lane]);
    float n0 = __half2float(__ushort_as_half((unsigned short)(e0 >> 16)));
    float n1 = __half2float(__ushort_as_half((unsigned short)(e1 >> 16)));
    float n2 = __half2float(__ushort_as_half((unsigned short)(e2 >> 16)));
    float n3 = __half2float(__ushort_as_half((unsigned short)(e3 >> 16)));
    a0 += n0 * v0.x + n1 * v1.x + n2 * v2.x + n3 * v3.x;
    a1 += n0 * v0.y + n1 * v1.y + n2 * v2.y + n3 * v3.y;
  }
  for (; idx < end; ++idx) {
    unsigned e = csrc[idx];
    float2 v = __half22float2(hc[(size_t)(e & 0xffffu) * 64 + lane]);
    float nm = __half2float(__ushort_as_half((unsigned short)(e >> 16)));
    a0 += nm * v.x;
    a1 += nm * v.y;
  }
  float dn = dis[c * NN + node];
  float sn = dn * dn;                                 // self-loop norm
  float2 hv = __half22float2(hc[(size_t)node * 64 + lane]);
  int f = lane * 2;
  a0 += sn * hv.x + bias[c * 128 + f];
  a1 += sn * hv.y + bias[c * 128 + f + 1];
  a0 = fmaxf(a0, 0.f);
  a1 = fmaxf(a1, 0.f);
  ((unsigned*)out)[((size_t)c * NN + node) * 64 + lane] = pack2h(a0, a1);
}

// ---------------------------------------------------------------------------
// agg2: F=64, one wave per node, half-wave edge split, shfl_xor(32) combine.
// fp32 final output.
// ---------------------------------------------------------------------------

__global__ __launch_bounds__(256) void agg2_kernel(const __half2* __restrict__ h,
                                                   const int* __restrict__ rowptr,
                                                   const unsigned* __restrict__ csr,
                                                   const float* __restrict__ dis,
                                                   const float* __restrict__ bias,
                                                   float* __restrict__ out) {
  int c  = blockIdx.x / BLK_AGG_REL;
  int bl = blockIdx.x - c * BLK_AGG_REL;
  int node = bl * 4 + (threadIdx.x >> 6);
  int lane = threadIdx.x & 63;
  int hf = lane >> 5;       // which half-wave
  int fl = lane & 31;       // feature-pair index

  const __half2* hc = h + (size_t)c * NN * 32;       // row = 32 half2
  const unsigned* csrc = csr + (size_t)c * EE;
  int beg = rowptr[c * (NN + 1) + node];
  int end = rowptr[c * (NN + 1) + node + 1];

  float a0 = 0.f, a1 = 0.f;
  int idx = beg + hf;
  for (; idx + 2 < end; idx += 4) {     // 2 edges per half per iter
    unsigned ea = csrc[idx], eb = csrc[idx + 2];
    float2 va = __half22float2(hc[(size_t)(ea & 0xffffu) * 32 + fl]);
    float2 vb = __half22float2(hc[(size_t)(eb & 0xffffu) * 32 + fl]);
    float na = __half2float(__ushort_as_half((unsigned short)(ea >> 16)));
    float nb = __half2float(__ushort_as_half((unsigned short)(eb >> 16)));
    a0 += na * va.x + nb * vb.x;
    a1 += na * va.y + nb * vb.y;
  }
  for (; idx < end; idx += 2) {
    unsigned e = csrc[idx];
    float2 v = __half22float2(hc[(size_t)(e & 0xffffu) * 32 + fl]);
    float nm = __half2float(__ushort_as_half((unsigned short)(e >> 16)));
    a0 += nm * v.x;
    a1 += nm * v.y;
  }
  a0 += __shfl_xor(a0, 32, 64);
  a1 += __shfl_xor(a1, 32, 64);
  if (hf == 0) {
    float dn = dis[c * NN + node];
    float sn = dn * dn;
    float2 hv = __half22float2(hc[(size_t)node * 32 + fl]);
    int f = fl * 2;
    a0 += sn * hv.x + bias[c * 64 + f];
    a1 += sn * hv.y + bias[c * 64 + f + 1];
    *(float2*)&out[((size_t)c * NN + node) * 64 + f] = make_float2(a0, a1);
  }
}

// ---------------------------------------------------------------------------
// Host launcher
// ---------------------------------------------------------------------------

extern "C" void kernel_launch(void* const* d_in, const int* in_sizes, int n_in,
                              void* d_out, int out_size, void* d_ws, size_t ws_size,
                              hipStream_t stream) {
  const float* x  = (const float*)d_in[0];   // [C][N][128]
  const int*   ei = (const int*)d_in[1];     // [C][2][E]
  const float* ew = (const float*)d_in[2];   // [C][E]
  const float* W1 = (const float*)d_in[3];   // [C][128][128]
  const float* b1 = (const float*)d_in[4];   // [C][128]
  const float* W2 = (const float*)d_in[5];   // [C][128][64]
  const float* b2 = (const float*)d_in[6];   // [C][64]
  float* out = (float*)d_out;                // [C][N][64]

  char* ws = (char*)d_ws;
  size_t off = 0;
  auto alloc = [&](size_t bytes) {
    size_t cur = off;
    off += (bytes + 255) & ~(size_t)255;
    return cur;
  };
  unsigned long long* packed = (unsigned long long*)(ws + alloc((size_t)CN * 8));
  float*    dis    = (float*)   (ws + alloc((size_t)CN * 4));
  int*      rowptr = (int*)     (ws + alloc((size_t)C_REL * (NN + 1) * 4));
  int*      bsum   = (int*)     (ws + alloc((size_t)C_REL * 256 * 4));
  unsigned* csr    = (unsigned*)(ws + alloc((size_t)CE * 4));
  __half*   h1     = (__half*)  (ws + alloc((size_t)CN * D_H * 2));   // h1/h2 (fp16)
  __half*   agg1h  = (__half*)  (ws + alloc((size_t)CN * D_H * 2));   // relu out (fp16)
  // pos[CE] (16MB) unions with agg1h (64MB): pos dead before agg1 writes.
  // NOTE: pos must NOT alias h1 (hist writes pos while gemm1 writes h1).
  int* pos = (int*)agg1h;

  const int NB_CN = (CN + 255) / 256;

  init_kernel<<<NB_CN, 256, 0, stream>>>(packed);
  // hist (atomic-bound) overlapped with gemm1 (VALU-bound, independent).
  fused_hist_gemm1_kernel<<<FUSED_GRID, 256, 0, stream>>>(x, W1, h1, ei, ew, packed, pos);
  dis_kernel<<<NB_CN, 256, 0, stream>>>(packed, dis);
  scan_a_kernel<<<C_REL * SCAN_B, 256, 0, stream>>>(packed, rowptr, bsum);
  scan_b_kernel<<<C_REL, 256, 0, stream>>>(bsum);
  scan_c_kernel<<<C_REL * SCAN_B, 256, 0, stream>>>(rowptr, bsum);
  fill_kernel<<<FILL_BLOCKS, 256, 0, stream>>>(ei, ew, dis, rowptr, pos, csr);

  agg1_kernel<<<C_REL * BLK_AGG_REL, 256, 0, stream>>>((const __half2*)h1, rowptr, csr,
                                                       dis, b1, agg1h);
  gemm2_kernel<<<C_REL * BLK_GEMM_REL, 256, 0, stream>>>(agg1h, W2, h1);
  agg2_kernel<<<C_REL * BLK_AGG_REL, 256, 0, stream>>>((const __half2*)h1, rowptr, csr,
                                                       dis, b2, out);
}